// Round 9
// baseline (101.744 us; speedup 1.0000x reference)
//
#include <hip/hip_runtime.h>
#include <hip/hip_fp16.h>
#include <math.h>

#define N      512
#define DIMC   128
#define HEADS  4
#define DH     32
#define INDC   5
#define SCALE  0.1767766952966369f   // 32^-0.5

// Virtual output rows of the fused pre-GEMM: all are (row_weights) @ x
//   rows [0,384)   : qkv   (q rows 0..127, k 128..255, v 256..383)
//   rows [384,404) : Aq[(h*5+c)]  composite weight  Wq_rows . W_ind_k
//   rows [404,424) : Ak[(h*5+c)]  composite weight  Wk_rows . W_ind_q
// rows are stored FP16 (halves attn L2 traffic; error << threshold)
#define QKV_ROWS 384
#define AQ_BASE  384
#define AK_BASE  404
#define TOT_ROWS 424
#define NROW_BLK (TOT_ROWS / 4)   // 106

// ws layout: [rows fp16][M raw 4x32 f32][w_outT 16384 f32]
#define MHS_F    (TOT_ROWS * N / 2)
#define WOUTT_F  (MHS_F + 128)

// ---------------- Kernel 1: fused pre-GEMM + M + w_out transpose ----------------
__global__ __launch_bounds__(256) void pre_kernel(const float* __restrict__ w_qkv,
                                                  const float* __restrict__ w_ind,
                                                  const float* __restrict__ x,
                                                  const float* __restrict__ w_out,
                                                  float* __restrict__ ws) {
    const int bx = blockIdx.x;
    const int t  = threadIdx.x;
    __half* rows  = (__half*)ws;
    float* MhS    = ws + MHS_F;
    float* w_outT = ws + WOUTT_F;

    if (bx == NROW_BLK) {
        if (blockIdx.y != 0) return;
        // --- M[h,c,cc] = sum_d w_ind_q[h,d,c] * w_ind_k[h,d,cc] (raw 5x5) ---
        if (t < HEADS * INDC * INDC) {
            const int h = t / 25, idx = t % 25, c = idx / 5, cc = idx % 5;
            float acc = 0.f;
            for (int d = 0; d < DH; ++d)
                acc = fmaf(w_ind[(h * DH + d) * INDC + c],
                           w_ind[(DIMC + h * DH + d) * INDC + cc], acc);
            MhS[h * 32 + idx] = acc;
        }
        // --- transpose w_out (128x128) so the fused outproj reads coalesced ---
        for (int idx = t; idx < DIMC * DIMC; idx += 256) {
            const int o = idx >> 7, c = idx & 127;
            w_outT[c * DIMC + o] = w_out[idx];
        }
        return;
    }

    // --- 4 virtual rows per block, c-major float4 layout in LDS ---
    __shared__ float ws2[4 * DIMC];   // ws2[c*4 + r]
    const int o0 = bx * 4;
    for (int idx = t; idx < 4 * DIMC; idx += 256) {
        const int r = idx & 3, m = idx >> 2;
        const int row = o0 + r;
        float val;
        if (row < QKV_ROWS) {
            val = w_qkv[row * DIMC + m];
        } else if (row < AK_BASE) {              // Aq composite: q-rows . W_ind_k
            const int rr = row - AQ_BASE, h = rr / INDC, c = rr % INDC;
            float acc = 0.f;
            for (int d = 0; d < DH; ++d)
                acc = fmaf(w_qkv[(h * DH + d) * DIMC + m],
                           w_ind[(DIMC + h * DH + d) * INDC + c], acc);
            val = acc;
        } else {                                  // Ak composite: k-rows . W_ind_q
            const int rr = row - AK_BASE, h = rr / INDC, c = rr % INDC;
            float acc = 0.f;
            for (int d = 0; d < DH; ++d)
                acc = fmaf(w_qkv[(DIMC + h * DH + d) * DIMC + m],
                           w_ind[(h * DH + d) * INDC + c], acc);
            val = acc;
        }
        ws2[m * 4 + r] = val;
    }
    __syncthreads();

    const int i = blockIdx.y * 256 + t;
    float acc[4] = {0.f, 0.f, 0.f, 0.f};
#pragma unroll 8
    for (int c = 0; c < DIMC; ++c) {
        const float xv = x[c * N + i];
        const float4 wv = *(const float4*)(ws2 + c * 4);
        acc[0] = fmaf(wv.x, xv, acc[0]);
        acc[1] = fmaf(wv.y, xv, acc[1]);
        acc[2] = fmaf(wv.z, xv, acc[2]);
        acc[3] = fmaf(wv.w, xv, acc[3]);
    }
#pragma unroll
    for (int r = 0; r < 4; ++r) rows[(o0 + r) * N + i] = __float2half(acc[r]);
}

// ---- Kernel 2: one block per i; wave h owns head h (barrier-free per wave),
//      then ONE __syncthreads and the fused 128x128 output projection. ----
__global__ __launch_bounds__(256) void attn_kernel(const float* __restrict__ ws_c,
                                                   const float* __restrict__ ind,
                                                   const float* __restrict__ b_out,
                                                   float* __restrict__ out) {
    const int t    = threadIdx.x;
    const int lane = t & 63;
    const int h    = t >> 6;          // wave = head
    const int i    = blockIdx.x;

    const __half* rows   = (const __half*)ws_c;
    const float*  Mh     = ws_c + MHS_F;
    const float*  w_outT = ws_c + WOUTT_F;

    __shared__ float psh[HEADS][N];   // 8 KB: per-wave P
    __shared__ float attv[DIMC];      // all heads' PV results
    __shared__ float outp[2][DIMC];   // outproj partials

    // ---- per-wave scalars ----
    const __half* q  = rows;
    const __half* Aq = rows + 3 * DIMC * N;
    const float qreg = __half2float(q[(h * DH + (lane & 31)) * N + i]); // lane d holds q_d
    float aq[INDC];
#pragma unroll
    for (int c = 0; c < INDC; ++c)
        aq[c] = __half2float(Aq[(h * INDC + c) * N + i]);   // same addr all lanes: broadcast
    float M[INDC * INDC];                                   // wave-uniform scalar loads
#pragma unroll
    for (int p = 0; p < INDC * INDC; ++p) M[p] = Mh[h * 32 + p];

    // ---- indicator: 8 consecutive j's per lane; all 4 waves share these rows (L1) ----
    float ic[INDC][8];
#pragma unroll
    for (int c = 0; c < INDC; ++c) {
        const float4* ip = (const float4*)(ind + (c * N + i) * N);
        *(float4*)&ic[c][0] = ip[lane * 2];
        *(float4*)&ic[c][4] = ip[lane * 2 + 1];
    }

    // ---- qk: 32 coalesced float4 K loads (8 halfs each) ----
    float s[8] = {0.f, 0.f, 0.f, 0.f, 0.f, 0.f, 0.f, 0.f};
    const float4* k4 = (const float4*)(rows + DIMC * N);    // row stride 64 float4
#pragma unroll
    for (int d = 0; d < DH; ++d) {
        const float qd = __shfl(qreg, d, 64);
        const float4 kv = k4[(h * DH + d) * 64 + lane];
        const __half2* kh = (const __half2*)&kv;
#pragma unroll
        for (int p = 0; p < 4; ++p) {
            const float2 kf = __half22float2(kh[p]);
            s[p * 2 + 0] = fmaf(qd, kf.x, s[p * 2 + 0]);
            s[p * 2 + 1] = fmaf(qd, kf.y, s[p * 2 + 1]);
        }
    }
    // ---- lin: (aq_c + Ak_c[j]) * ic_c[j] ----
    const float4* ak4 = (const float4*)(rows + (3 * DIMC + HEADS * INDC) * N);
#pragma unroll
    for (int c = 0; c < INDC; ++c) {
        const float4 av = ak4[(h * INDC + c) * 64 + lane];
        const __half2* ah = (const __half2*)&av;
#pragma unroll
        for (int p = 0; p < 4; ++p) {
            const float2 af = __half22float2(ah[p]);
            s[p * 2 + 0] = fmaf(aq[c] + af.x, ic[c][p * 2 + 0], s[p * 2 + 0]);
            s[p * 2 + 1] = fmaf(aq[c] + af.y, ic[c][p * 2 + 1], s[p * 2 + 1]);
        }
    }
    // ---- quad: ic^T M ic per j ----
#pragma unroll
    for (int j = 0; j < 8; ++j) {
        float acc = 0.f;
#pragma unroll
        for (int c = 0; c < INDC; ++c) {
            float tc = 0.f;
#pragma unroll
            for (int cc = 0; cc < INDC; ++cc)
                tc = fmaf(M[c * INDC + cc], ic[cc][j], tc);
            acc = fmaf(ic[c][j], tc, acc);
        }
        s[j] = SCALE * (s[j] + acc);
    }

    // ---- softmax across the wave (512 j) — pure shuffles, no barrier ----
    float m = s[0];
#pragma unroll
    for (int j = 1; j < 8; ++j) m = fmaxf(m, s[j]);
#pragma unroll
    for (int off = 32; off; off >>= 1) m = fmaxf(m, __shfl_xor(m, off, 64));
    float e[8], sum = 0.f;
#pragma unroll
    for (int j = 0; j < 8; ++j) { e[j] = __expf(s[j] - m); sum += e[j]; }
#pragma unroll
    for (int off = 32; off; off >>= 1) sum += __shfl_xor(sum, off, 64);
    const float rs = 1.f / sum;
#pragma unroll
    for (int j = 0; j < 8; ++j) e[j] *= rs;

    // ---- stage P in per-wave LDS (intra-wave: no barrier needed) ----
    *(float4*)&psh[h][lane * 8]     = make_float4(e[0], e[1], e[2], e[3]);
    *(float4*)&psh[h][lane * 8 + 4] = make_float4(e[4], e[5], e[6], e[7]);

    // ---- PV: lane (d, half) sums its 256 j's; LDS reads broadcast ----
    {
        const int d = lane & 31, half = lane >> 5;
        const float4* v4 = (const float4*)(rows + 2 * DIMC * N);
        const float4* pf = (const float4*)&psh[h][0];
        float acc = 0.f;
#pragma unroll
        for (int kk = 0; kk < 32; ++kk) {
            const float4 vv = v4[(h * DH + d) * 64 + half * 32 + kk];  // 8 j's
            const float4 p0 = pf[half * 64 + kk * 2];
            const float4 p1 = pf[half * 64 + kk * 2 + 1];
            const __half2* vh = (const __half2*)&vv;
            const float2 f0 = __half22float2(vh[0]);
            const float2 f1 = __half22float2(vh[1]);
            const float2 f2 = __half22float2(vh[2]);
            const float2 f3 = __half22float2(vh[3]);
            acc = fmaf(p0.x, f0.x, acc); acc = fmaf(p0.y, f0.y, acc);
            acc = fmaf(p0.z, f1.x, acc); acc = fmaf(p0.w, f1.y, acc);
            acc = fmaf(p1.x, f2.x, acc); acc = fmaf(p1.y, f2.y, acc);
            acc = fmaf(p1.z, f3.x, acc); acc = fmaf(p1.w, f3.y, acc);
        }
        acc += __shfl_xor(acc, 32, 64);              // combine the two j-halves
        if (lane < 32) attv[h * DH + d] = acc;
    }
    __syncthreads();

    // ---- fused output projection: out[:, i] = w_out @ attv + b_out ----
    {
        const int o = t & 127, phase = t >> 7;       // 2 threads per o, 64 c each
        float acc = 0.f;
#pragma unroll 8
        for (int c = phase * 64; c < phase * 64 + 64; ++c)
            acc = fmaf(w_outT[c * DIMC + o], attv[c], acc);
        outp[phase][o] = acc;
    }
    __syncthreads();
    if (t < DIMC)
        out[t * N + i] = outp[0][t] + outp[1][t] + b_out[t];
}

extern "C" void kernel_launch(void* const* d_in, const int* in_sizes, int n_in,
                              void* d_out, int out_size, void* d_ws, size_t ws_size,
                              hipStream_t stream) {
    const float* x         = (const float*)d_in[0];  // (1,128,512)
    const float* indicator = (const float*)d_in[1];  // (1,5,512,512)
    const float* w_qkv     = (const float*)d_in[2];  // (384,128)
    const float* w_ind     = (const float*)d_in[3];  // (256,5)
    const float* w_out     = (const float*)d_in[4];  // (128,128)
    const float* b_out     = (const float*)d_in[5];  // (128,)
    float* out = (float*)d_out;                      // (1,128,512)
    float* ws  = (float*)d_ws;

    pre_kernel<<<dim3(NROW_BLK + 1, 2), 256, 0, stream>>>(w_qkv, w_ind, x, w_out, ws);
    attn_kernel<<<N, 256, 0, stream>>>(ws, indicator, b_out, out);
}